// Round 1
// baseline (3103.697 us; speedup 1.0000x reference)
//
#include <hip/hip_runtime.h>
#include <hip/hip_bf16.h>
#include <cstddef>

#define H   50
#define G4  200   // 4*H
#define TT  1024
#define BB  512

__device__ __forceinline__ float sigm(float x) { return 1.0f / (1.0f + __expf(-x)); }
__device__ __forceinline__ float tanh_fast(float x) { return 1.0f - 2.0f / (__expf(2.0f * x) + 1.0f); }

// dot of 50 with 4 accumulators (w is a register array after inlining; v is LDS)
__device__ __forceinline__ float dot50(const float* __restrict__ w, const float* __restrict__ v) {
    float a0 = 0.f, a1 = 0.f, a2 = 0.f, a3 = 0.f;
#pragma unroll
    for (int k = 0; k < 48; k += 4) {
        a0 = __fmaf_rn(w[k + 0], v[k + 0], a0);
        a1 = __fmaf_rn(w[k + 1], v[k + 1], a1);
        a2 = __fmaf_rn(w[k + 2], v[k + 2], a2);
        a3 = __fmaf_rn(w[k + 3], v[k + 3], a3);
    }
    a0 = __fmaf_rn(w[48], v[48], a0);
    a1 = __fmaf_rn(w[49], v[49], a1);
    return (a0 + a2) + (a1 + a3);
}

// MODE 0: first layer (scalar x input, write h-seq)
// MODE 1: middle layer (vector input, write h-seq; in-place on ws is safe)
// MODE 2: last layer (vector input, no h-seq write, fused dense head)
template <int MODE>
__global__ __launch_bounds__(256, 2) void lstm_kernel(
    const float* __restrict__ xin,     // MODE0: x [B][T]; else h_prev [B][T][H]
    const float* __restrict__ w_ih,    // [G4][H] (MODE0: [G4][1])
    const float* __restrict__ w_hh,    // [G4][H]
    const float* __restrict__ b_ih,    // [G4]
    const float* __restrict__ b_hh,    // [G4]
    float* __restrict__ hout,          // [B][T][H]  (MODE 0,1)
    const float* __restrict__ w_dense, // [H]    (MODE 2)
    const float* __restrict__ b_dense, // [1]    (MODE 2)
    float* __restrict__ out)           // [B]    (MODE 2)
{
    const int b  = blockIdx.x;
    const int tid = threadIdx.x;
    const int wv = tid >> 6;   // wave index 0..3
    const int ln = tid & 63;   // lane

    __shared__ float h_s[4][64];       // per-wave h copy (broadcast reads, no cross-wave dep)
    __shared__ float gates_s[2][256];  // double-buffered gate pre-activations
    __shared__ float xin_s[2][64];     // MODE 1,2: double-buffered x_t
    __shared__ float x_s[TT];          // MODE 0: whole input row (4 KB)

    // ---- per-thread weights in registers ----
    float wih_r[H];
    float whh_r[H];
    float bias_r = 0.f;
    const int g = tid;
    if (g < G4) {
        bias_r = b_ih[g] + b_hh[g];
#pragma unroll
        for (int k = 0; k < H; k++) whh_r[k] = w_hh[g * H + k];
        if (MODE == 0) {
            wih_r[0] = w_ih[g];
#pragma unroll
            for (int k = 1; k < H; k++) wih_r[k] = 0.f;
        } else {
#pragma unroll
            for (int k = 0; k < H; k++) wih_r[k] = w_ih[g * H + k];
        }
    } else {
#pragma unroll
        for (int k = 0; k < H; k++) { whh_r[k] = 0.f; wih_r[k] = 0.f; }
    }
    float wd_r = 0.f;
    if (MODE == 2 && ln < H) wd_r = w_dense[ln];

    // ---- init LDS state + stage inputs ----
    h_s[wv][ln] = 0.f;
    if (MODE == 0) {
        for (int i = tid; i < TT; i += 256) x_s[i] = xin[(size_t)b * TT + i];
    } else {
        if (tid < H) xin_s[0][tid] = xin[(size_t)b * TT * H + tid];
    }
    float c_r = 0.f;     // cell state (replicated per wave, lanes < H)
    float hval = 0.f;    // last h (MODE 2 dense)
    __syncthreads();

    for (int t = 0; t < TT; t++) {
        const int p = t & 1;
        // ---- phase 1: gate pre-activations ----
        float acc = bias_r;
        if (MODE == 0) {
            acc = __fmaf_rn(wih_r[0], x_s[t], acc);
        } else {
            acc += dot50(wih_r, xin_s[p]);
        }
        acc += dot50(whh_r, h_s[wv]);
        if (g < G4) gates_s[p][g] = acc;
        // prefetch next step's input vector (idle threads of wave 3)
        if (MODE != 0) {
            if (g >= G4 && g < G4 + H && t + 1 < TT)
                xin_s[p ^ 1][g - G4] = xin[(size_t)b * TT * H + (size_t)(t + 1) * H + (g - G4)];
        }
        __syncthreads();   // the ONLY barrier per step
        // ---- phase 2: elementwise update, redundant in every wave ----
        if (ln < H) {
            float iv = sigm(gates_s[p][ln]);
            float fv = sigm(gates_s[p][H + ln]);
            float gv = tanh_fast(gates_s[p][2 * H + ln]);
            float ov = sigm(gates_s[p][3 * H + ln]);
            c_r = __fmaf_rn(fv, c_r, iv * gv);
            hval = ov * tanh_fast(c_r);
            h_s[wv][ln] = hval;
            if (MODE != 2 && wv == 0)
                hout[(size_t)b * TT * H + (size_t)t * H + ln] = hval;
        }
        // next phase-1 reads h_s[wv] — same-wave dependency, lgkmcnt only, no barrier
    }

    // ---- dense head (MODE 2): out[b] = h_last . w_dense + b_dense ----
    if (MODE == 2 && wv == 0) {
        float v = (ln < H) ? hval * wd_r : 0.f;
#pragma unroll
        for (int off = 32; off > 0; off >>= 1) v += __shfl_down(v, off, 64);
        if (ln == 0) out[b] = v + b_dense[0];
    }
}

extern "C" void kernel_launch(void* const* d_in, const int* in_sizes, int n_in,
                              void* d_out, int out_size, void* d_ws, size_t ws_size,
                              hipStream_t stream) {
    const float* x     = (const float*)d_in[0];
    const float* wih1  = (const float*)d_in[1];
    const float* whh1  = (const float*)d_in[2];
    const float* bih1  = (const float*)d_in[3];
    const float* bhh1  = (const float*)d_in[4];
    const float* wih2  = (const float*)d_in[5];
    const float* whh2  = (const float*)d_in[6];
    const float* bih2  = (const float*)d_in[7];
    const float* bhh2  = (const float*)d_in[8];
    const float* wih3  = (const float*)d_in[9];
    const float* whh3  = (const float*)d_in[10];
    const float* bih3  = (const float*)d_in[11];
    const float* bhh3  = (const float*)d_in[12];
    const float* wd    = (const float*)d_in[13];
    const float* bd    = (const float*)d_in[14];
    float* outp = (float*)d_out;
    float* hbuf = (float*)d_ws;   // [B][T][H] fp32, used in-place by all layers

    lstm_kernel<0><<<BB, 256, 0, stream>>>(x,    wih1, whh1, bih1, bhh1, hbuf, nullptr, nullptr, nullptr);
    lstm_kernel<1><<<BB, 256, 0, stream>>>(hbuf, wih2, whh2, bih2, bhh2, hbuf, nullptr, nullptr, nullptr);
    lstm_kernel<2><<<BB, 256, 0, stream>>>(hbuf, wih3, whh3, bih3, bhh3, nullptr, wd, bd, outp);
}